// Round 1
// baseline (16993.687 us; speedup 1.0000x reference)
//
#include <hip/hip_runtime.h>
#include <cmath>

#define BATCH 256
#define TSEQ  256
#define ISZ   32
#define HSZ   512
#define OSZ   32
#define FUT   128

__device__ __forceinline__ float sigm(float x) { return 1.0f / (1.0f + expf(-x)); }

// One LSTM time step.
// Grid: 512 WGs = 4 batch-groups x 128 n-groups. Block: 256 threads = 4 waves.
// Wave w of a WG owns hidden column n = ng*4 + w (wave-uniform -> scalar loads
// for all weight traffic). Lane = batch row within the 64-row batch group.
// h and c live transposed [H][B] so lane-indexed accesses are coalesced.
// h is double-buffered (read hT_old, write hT_new) to avoid cross-WG races.
__global__ __launch_bounds__(256) void lstm_step_kernel(
    const float* __restrict__ xbase, int xrb, int xrk,
    const float* __restrict__ W_ih, const float* __restrict__ W_hh,
    const float* __restrict__ b_ih, const float* __restrict__ b_hh,
    const float* __restrict__ hT_old, float* __restrict__ hT_new,
    float* __restrict__ cT)
{
    const int bg   = blockIdx.x & 3;
    const int ng   = blockIdx.x >> 2;
    const int wave = __builtin_amdgcn_readfirstlane((int)(threadIdx.x >> 6));
    const int lane = (int)(threadIdx.x & 63);
    const int n    = ng * 4 + wave;   // wave-uniform hidden column
    const int b    = bg * 64 + lane;  // batch row

    // PyTorch gate layout [i, f, g, o] stacked along 4H.
    float acc0 = b_ih[n]        + b_hh[n];
    float acc1 = b_ih[n + 512]  + b_hh[n + 512];
    float acc2 = b_ih[n + 1024] + b_hh[n + 1024];
    float acc3 = b_ih[n + 1536] + b_hh[n + 1536];

    // x contribution (K = 32). Encoder: xrb = T*I, xrk = 1 (row-major x).
    // Decoder: xrb = 1, xrk = BATCH (transposed pred buffer).
    #pragma unroll 8
    for (int k = 0; k < ISZ; ++k) {
        float xv = xbase[b * xrb + k * xrk];
        acc0 += xv * W_ih[(n)        * ISZ + k];
        acc1 += xv * W_ih[(n + 512)  * ISZ + k];
        acc2 += xv * W_ih[(n + 1024) * ISZ + k];
        acc3 += xv * W_ih[(n + 1536) * ISZ + k];
    }

    // h contribution (K = 512). Coalesced per-wave 256B loads from hT_old.
    #pragma unroll 8
    for (int k = 0; k < HSZ; ++k) {
        float hv = hT_old[k * BATCH + b];
        acc0 += hv * W_hh[(n)        * HSZ + k];
        acc1 += hv * W_hh[(n + 512)  * HSZ + k];
        acc2 += hv * W_hh[(n + 1024) * HSZ + k];
        acc3 += hv * W_hh[(n + 1536) * HSZ + k];
    }

    const float ig = sigm(acc0);
    const float fg = sigm(acc1);
    const float gg = tanhf(acc2);
    const float og = sigm(acc3);

    const int idx = n * BATCH + b;
    const float cn = fg * cT[idx] + ig * gg;
    cT[idx]     = cn;
    hT_new[idx] = og * tanhf(cn);
}

// pred = h @ W_fc^T + b_fc. Writes both the transposed pred buffer (decoder
// input) and the output slice out[:, t, :].
__global__ __launch_bounds__(256) void fc_kernel(
    const float* __restrict__ hT, const float* __restrict__ W_fc,
    const float* __restrict__ b_fc,
    float* __restrict__ predT, float* __restrict__ out_t)
{
    const int tid = blockIdx.x * 256 + (int)threadIdx.x; // 8192 threads
    const int b = tid >> 5;
    const int o = tid & 31;

    float acc = b_fc[o];
    #pragma unroll 8
    for (int k = 0; k < HSZ; ++k) {
        acc += hT[k * BATCH + b] * W_fc[o * HSZ + k];
    }
    predT[o * BATCH + b]        = acc;
    out_t[b * (FUT * OSZ) + o]  = acc;
}

extern "C" void kernel_launch(void* const* d_in, const int* in_sizes, int n_in,
                              void* d_out, int out_size, void* d_ws, size_t ws_size,
                              hipStream_t stream)
{
    const float* x    = (const float*)d_in[0];
    const float* W_ih = (const float*)d_in[1];
    const float* W_hh = (const float*)d_in[2];
    const float* b_ih = (const float*)d_in[3];
    const float* b_hh = (const float*)d_in[4];
    const float* W_fc = (const float*)d_in[5];
    const float* b_fc = (const float*)d_in[6];
    float* out = (float*)d_out;

    char* ws = (char*)d_ws;
    float* h0    = (float*)(ws);                    // [H][B] 512 KB
    float* cT    = (float*)(ws + (512u  << 10));    // [H][B] 512 KB
    float* h1    = (float*)(ws + (1024u << 10));    // [H][B] 512 KB
    float* predT = (float*)(ws + (1536u << 10));    // [I][B]  32 KB

    // Zero h0 and cT (contiguous first 1 MB). Graph-capturable.
    hipMemsetAsync(ws, 0, 1024u << 10, stream);

    float* hcur = h0;
    float* hnxt = h1;

    // ---- encoder ----
    for (int t = 0; t < TSEQ; ++t) {
        lstm_step_kernel<<<512, 256, 0, stream>>>(
            x + (size_t)t * ISZ, TSEQ * ISZ, 1,
            W_ih, W_hh, b_ih, b_hh, hcur, hnxt, cT);
        float* tmp = hcur; hcur = hnxt; hnxt = tmp;
    }

    // ---- autoregressive decoder ----
    for (int t = 0; t < FUT; ++t) {
        fc_kernel<<<32, 256, 0, stream>>>(hcur, W_fc, b_fc, predT, out + (size_t)t * OSZ);
        lstm_step_kernel<<<512, 256, 0, stream>>>(
            predT, 1, BATCH,
            W_ih, W_hh, b_ih, b_hh, hcur, hnxt, cT);
        float* tmp = hcur; hcur = hnxt; hnxt = tmp;
    }
}